// Round 4
// baseline (261.932 us; speedup 1.0000x reference)
//
#include <hip/hip_runtime.h>

// Problem: B=2, S=2048, D=512, H=8, dh=64.
// R7 (resubmit; R3 was a GPU-acquisition timeout, kernel never ran):
// single REGULAR launch (no cooperative API — it failed under the harness),
// fused phases with a hand-rolled device-scope dependency barrier.
//   Phase 1 (qgemm): Q = X @ Wq via bf16 MFMA, fp32->bf16 cast in registers,
//     swizzled LDS staging, next-tile loads under MFMAs. 8 waves/block, wave
//     (rg,cg) owns rows rg*16..+16, col half cg. t[h] = Wh^T Wv during B
//     staging. Epilogue: Qh bf16, nl = -0.125*log2e*||Q_head||, y = Q.t[h].
//   Barrier: per-(b,h) counters. Phase-1 block (h, m0) arrives at
//     cnt[bb*8+h] (threadfence release + atomicAdd). Phase-2 block for bh
//     spins until cnt[bh]==32 (RMW spin + s_sleep), threadfence acquire.
//     Co-residency guaranteed: 512 blocks == 2 blocks/CU * 256 CU exactly
//     (launch_bounds(512,4) -> VGPR<=128, LDS 23.5KB) -> no deadlock.
//   Phase 2 (attn): out = sigmoid( softmax((2QQ^T - n_s - n_t)/8) @ y ).
//     -n_s cancels in softmax; exp2 args bounded -> fp32-safe. Waves own
//     disjoint t-ranges; B-frags straight from global (L2-resident);
//     zero barriers in the main loop.

typedef __attribute__((ext_vector_type(8))) short bf16x8;
typedef __attribute__((ext_vector_type(4))) float f32x4;

#if __has_builtin(__builtin_amdgcn_exp2f)
#define EXP2F(x) __builtin_amdgcn_exp2f(x)
#else
#define EXP2F(x) exp2f(x)
#endif

#define LOG2E 1.44269504088896341f
#define C025  (0.25f * LOG2E)
#define C0125 (0.125f * LOG2E)

__device__ inline unsigned int f2b(float f) {  // fp32 -> bf16 bits, RNE
    unsigned int u = __float_as_uint(f);
    return (u + 0x7fffu + ((u >> 16) & 1u)) >> 16;
}

// swizzled LDS tile: row stride 64 bf16 (128B), 16B chunk c at (c ^ (row&7))
#define SWZ(row, c) ((row) * 64 + (((c) ^ ((row) & 7)) * 8))

__global__ __launch_bounds__(512, 4) void fused_k(const float* __restrict__ X,
                                                  const float* __restrict__ Wq,
                                                  const float* __restrict__ Wv,
                                                  unsigned short* __restrict__ Qh,
                                                  float* __restrict__ nl_ws,
                                                  float* __restrict__ y_ws,
                                                  unsigned int* __restrict__ cnt,
                                                  float* __restrict__ out) {
    __shared__ __align__(16) unsigned short As[64 * 64];
    __shared__ __align__(16) unsigned short Bs[64 * 64];
    __shared__ float tsh[512];
    __shared__ float redS[2][64], redY[2][64];
    __shared__ float redN[8][64], redD[8][64];

    int tid = threadIdx.x;
    int bid = blockIdx.x;
    int w = tid >> 6, lane = tid & 63;
    int tt = lane & 15, quad = lane >> 4;

    // ---------------- Phase 1: Q-GEMM ----------------
    {
        int h = bid & 7;
        int m0 = (bid >> 3) * 64;
        int n0 = h * 64;
        int rg = w >> 1, cg = w & 1;

        int arow = tid >> 3, achk = tid & 7;   // A staging: 64 rows x 8 chunks
        int bc = tid & 63, bjg = tid >> 6;     // B staging: 64 cols x 8 chunks

        const float* Xa = &X[(m0 + arow) * 512 + achk * 8];
        const float* Wb = &Wq[n0 + bc];

        float4 a0v, a1v;
        float bv[8], wvv[8];
        float tp = 0.f;
        f32x4 acc[2] = {{0.f,0.f,0.f,0.f},{0.f,0.f,0.f,0.f}};

#define LOADS(K0)                                                    \
        do {                                                         \
            a0v = *(const float4*)&Xa[(K0)];                         \
            a1v = *(const float4*)&Xa[(K0) + 4];                     \
            _Pragma("unroll")                                        \
            for (int i = 0; i < 8; ++i) {                            \
                bv[i]  = Wb[((K0) + bjg * 8 + i) * 512];             \
                wvv[i] = Wv[(K0) + bjg * 8 + i];                     \
            }                                                        \
        } while (0)

        LOADS(0);
        for (int k0 = 0; k0 < 512; k0 += 64) {
            __syncthreads();             // prev compute done reading LDS
            uint4 o;
            o.x = f2b(a0v.x) | (f2b(a0v.y) << 16);
            o.y = f2b(a0v.z) | (f2b(a0v.w) << 16);
            o.z = f2b(a1v.x) | (f2b(a1v.y) << 16);
            o.w = f2b(a1v.z) | (f2b(a1v.w) << 16);
            *(uint4*)&As[SWZ(arow, achk)] = o;
            o.x = f2b(bv[0]) | (f2b(bv[1]) << 16);
            o.y = f2b(bv[2]) | (f2b(bv[3]) << 16);
            o.z = f2b(bv[4]) | (f2b(bv[5]) << 16);
            o.w = f2b(bv[6]) | (f2b(bv[7]) << 16);
            *(uint4*)&Bs[SWZ(bc, bjg)] = o;
            #pragma unroll
            for (int i = 0; i < 8; ++i) tp = fmaf(bv[i], wvv[i], tp);
            __syncthreads();
            if (k0 < 448) LOADS(k0 + 64);   // next-tile loads overlap MFMAs
            int ar = rg * 16 + tt;
            bf16x8 fa0 = *(const bf16x8*)&As[SWZ(ar, quad)];
            bf16x8 fa1 = *(const bf16x8*)&As[SWZ(ar, quad + 4)];
            #pragma unroll
            for (int c = 0; c < 2; ++c) {
                int br = (cg * 2 + c) * 16 + tt;
                bf16x8 fb0 = *(const bf16x8*)&Bs[SWZ(br, quad)];
                bf16x8 fb1 = *(const bf16x8*)&Bs[SWZ(br, quad + 4)];
                acc[c] = __builtin_amdgcn_mfma_f32_16x16x32_bf16(fa0, fb0, acc[c], 0, 0, 0);
                acc[c] = __builtin_amdgcn_mfma_f32_16x16x32_bf16(fa1, fb1, acc[c], 0, 0, 0);
            }
        }

        tsh[bjg * 64 + bc] = tp;          // t[h] partials: 8 k-groups per col
        __syncthreads();
        float tv[2];
        #pragma unroll
        for (int c = 0; c < 2; ++c) {
            int col = (cg * 2 + c) * 16 + tt;
            float s = 0.f;
            #pragma unroll
            for (int j = 0; j < 8; ++j) s += tsh[j * 64 + col];
            tv[c] = s;
        }

        float s2[4] = {0.f,0.f,0.f,0.f}, yp[4] = {0.f,0.f,0.f,0.f};
        #pragma unroll
        for (int c = 0; c < 2; ++c)
            #pragma unroll
            for (int g = 0; g < 4; ++g) {
                float v = acc[c][g];
                s2[g] = fmaf(v, v, s2[g]);
                yp[g] = fmaf(v, tv[c], yp[g]);
                Qh[(m0 + rg * 16 + quad * 4 + g) * 512 + n0 + (cg * 2 + c) * 16 + tt] =
                    (unsigned short)f2b(v);
            }
        #pragma unroll
        for (int off = 1; off <= 8; off <<= 1)
            #pragma unroll
            for (int g = 0; g < 4; ++g) {
                s2[g] += __shfl_xor(s2[g], off);
                yp[g] += __shfl_xor(yp[g], off);
            }
        if (tt == 0) {
            #pragma unroll
            for (int g = 0; g < 4; ++g) {
                redS[cg][rg * 16 + quad * 4 + g] = s2[g];
                redY[cg][rg * 16 + quad * 4 + g] = yp[g];
            }
        }
        __syncthreads();
        if (tid < 64) {
            float s = redS[0][tid] + redS[1][tid];
            float y = redY[0][tid] + redY[1][tid];
            int bb = m0 >> 11;
            int idx = ((bb * 8 + h) << 11) + ((m0 + tid) & 2047);
            nl_ws[idx] = -C0125 * sqrtf(s);   // pre-scaled -0.125*log2e*n
            y_ws[idx] = y;
        }
    }

    // ---------------- Dependency barrier (device scope) ----------------
    {
        int g1 = (bid >> 8) * 8 + (bid & 7);   // this block produced (bb, h) rows
        int bh2 = bid >> 5;                    // this block will consume bh2
        __syncthreads();                       // all phase-1 stores issued+drained
        __threadfence();                       // release: writeback to coherence pt
        if (tid == 0) {
            atomicAdd(&cnt[g1], 1u);
            while (atomicAdd(&cnt[bh2], 0u) < 32u)   // device-scope RMW: coherent
                __builtin_amdgcn_s_sleep(4);
        }
        __syncthreads();
        __threadfence();                       // acquire: invalidate stale caches
    }

    // ---------------- Phase 2: attention ----------------
    {
        int bh = bid >> 5;              // 16 bh x 32 tiles
        int tile = bid & 31;
        int s0 = tile * 64;
        int b = bh >> 3, h = bh & 7;
        const unsigned short* Qb = Qh + (size_t)(b * 2048) * 512 + h * 64;
        const float* nb = nl_ws + bh * 2048;
        const float* yb = y_ws + bh * 2048;

        bf16x8 fa0[4], fa1[4];
        #pragma unroll
        for (int tl = 0; tl < 4; ++tl) {
            const unsigned short* r = &Qb[(size_t)(s0 + tl * 16 + tt) * 512];
            fa0[tl] = *(const bf16x8*)&r[quad * 8];
            fa1[tl] = *(const bf16x8*)&r[32 + quad * 8];
        }
        f32x4 num[4] = {{0.f,0.f,0.f,0.f},{0.f,0.f,0.f,0.f},
                        {0.f,0.f,0.f,0.f},{0.f,0.f,0.f,0.f}};
        f32x4 den[4] = {{0.f,0.f,0.f,0.f},{0.f,0.f,0.f,0.f},
                        {0.f,0.f,0.f,0.f},{0.f,0.f,0.f,0.f}};

        for (int st = 0; st < 16; ++st) {
            int tbase = w * 256 + st * 16;
            const unsigned short* rT = &Qb[(size_t)(tbase + tt) * 512];
            bf16x8 fb0 = *(const bf16x8*)&rT[quad * 8];
            bf16x8 fb1 = *(const bf16x8*)&rT[32 + quad * 8];
            float tqv = nb[tbase + tt];          // = -0.125*log2e*n_t
            float yv  = yb[tbase + tt];
            #pragma unroll
            for (int tl = 0; tl < 4; ++tl) {
                f32x4 dot = {0.f, 0.f, 0.f, 0.f};
                dot = __builtin_amdgcn_mfma_f32_16x16x32_bf16(fa0[tl], fb0, dot, 0, 0, 0);
                dot = __builtin_amdgcn_mfma_f32_16x16x32_bf16(fa1[tl], fb1, dot, 0, 0, 0);
                #pragma unroll
                for (int g = 0; g < 4; ++g) {
                    float arg = fmaf(C025, dot[g], tqv);
                    float e = EXP2F(arg);
                    num[tl][g] = fmaf(e, yv, num[tl][g]);
                    den[tl][g] += e;
                }
            }
        }

        #pragma unroll
        for (int off = 1; off <= 8; off <<= 1)
            #pragma unroll
            for (int tl = 0; tl < 4; ++tl)
                #pragma unroll
                for (int g = 0; g < 4; ++g) {
                    num[tl][g] += __shfl_xor(num[tl][g], off);
                    den[tl][g] += __shfl_xor(den[tl][g], off);
                }
        if (tt == 0) {
            #pragma unroll
            for (int tl = 0; tl < 4; ++tl)
                #pragma unroll
                for (int g = 0; g < 4; ++g) {
                    redN[w][tl * 16 + quad * 4 + g] = num[tl][g];
                    redD[w][tl * 16 + quad * 4 + g] = den[tl][g];
                }
        }
        __syncthreads();
        if (tid < 64) {
            float xn = 0.f, xd = 0.f;
            #pragma unroll
            for (int ww = 0; ww < 8; ++ww) {
                xn += redN[ww][tid];
                xd += redD[ww][tid];
            }
            float x = xn / xd;
            out[bh * 2048 + s0 + tid] = 1.0f / (1.0f + EXP2F(-x * LOG2E));
        }
    }
}

extern "C" void kernel_launch(void* const* d_in, const int* in_sizes, int n_in,
                              void* d_out, int out_size, void* d_ws, size_t ws_size,
                              hipStream_t stream) {
    const float* X  = (const float*)d_in[0];
    const float* Wq = (const float*)d_in[1];
    const float* Wv = (const float*)d_in[2];
    float* outp = (float*)d_out;
    float* ws = (float*)d_ws;

    float* nl_ws = ws;                                        // 32768 floats
    float* y_ws  = ws + 32768;                                // 32768 floats
    unsigned int* cnt_ws = (unsigned int*)(ws + 65536);       // 16 counters
    unsigned short* Qh_ws = (unsigned short*)(ws + 65552);    // 2M bf16 (16B-aligned)

    hipMemsetAsync(cnt_ws, 0, 64, stream);                    // zero barrier counters
    fused_k<<<512, 512, 0, stream>>>(X, Wq, Wv, Qh_ws, nl_ws, y_ws, cnt_ws, outp);
}

// Round 5
// 246.630 us; speedup vs baseline: 1.0620x; 1.0620x over previous
//
#include <hip/hip_runtime.h>

// Problem: B=2, S=2048, D=512, H=8, dh=64.
// R8 = R7 with the barrier spin fixed:
//   R7's spin was atomicAdd(&cnt,0) (device RMW) with all 16 counters in ONE
//   cacheline -> 512 spinners serialized on exclusive ownership -> 216us.
//   R8: load-only poll via __hip_atomic_load(RELAXED, AGENT scope), counters
//   padded to 128B each. Arrivals remain atomicAdd (32 per counter).
// Structure unchanged:
//   Phase 1 (qgemm): Q = X @ Wq via bf16 MFMA, fp32->bf16 cast in registers,
//     swizzled LDS staging, next-tile loads under MFMAs. t[h] = Wh^T Wv
//     during B staging. Epilogue: Qh bf16, nl = -0.125*log2e*||Q||, y = Q.t.
//   Barrier: per-(b,h) padded counters; release fence + atomicAdd arrive;
//     consumer load-spins until 32, then acquire fence. Co-residency
//     guaranteed: 512 blocks = 2/CU x 256 CU (VGPR<=128, LDS 23.5KB).
//   Phase 2 (attn): out = sigmoid( softmax((2QQ^T - n_s - n_t)/8) @ y ).
//     Waves own disjoint t-ranges; B-frags from global (L2/L3-resident);
//     zero barriers in the main loop.

typedef __attribute__((ext_vector_type(8))) short bf16x8;
typedef __attribute__((ext_vector_type(4))) float f32x4;

#if __has_builtin(__builtin_amdgcn_exp2f)
#define EXP2F(x) __builtin_amdgcn_exp2f(x)
#else
#define EXP2F(x) exp2f(x)
#endif

#define LOG2E 1.44269504088896341f
#define C025  (0.25f * LOG2E)
#define C0125 (0.125f * LOG2E)

#define CNT_STRIDE 32   // 32 uints = 128 B per counter

__device__ inline unsigned int f2b(float f) {  // fp32 -> bf16 bits, RNE
    unsigned int u = __float_as_uint(f);
    return (u + 0x7fffu + ((u >> 16) & 1u)) >> 16;
}

// swizzled LDS tile: row stride 64 bf16 (128B), 16B chunk c at (c ^ (row&7))
#define SWZ(row, c) ((row) * 64 + (((c) ^ ((row) & 7)) * 8))

__global__ __launch_bounds__(512, 4) void fused_k(const float* __restrict__ X,
                                                  const float* __restrict__ Wq,
                                                  const float* __restrict__ Wv,
                                                  unsigned short* __restrict__ Qh,
                                                  float* __restrict__ nl_ws,
                                                  float* __restrict__ y_ws,
                                                  unsigned int* __restrict__ cnt,
                                                  float* __restrict__ out) {
    __shared__ __align__(16) unsigned short As[64 * 64];
    __shared__ __align__(16) unsigned short Bs[64 * 64];
    __shared__ float tsh[512];
    __shared__ float redS[2][64], redY[2][64];
    __shared__ float redN[8][64], redD[8][64];

    int tid = threadIdx.x;
    int bid = blockIdx.x;
    int w = tid >> 6, lane = tid & 63;
    int tt = lane & 15, quad = lane >> 4;

    // ---------------- Phase 1: Q-GEMM ----------------
    {
        int h = bid & 7;
        int m0 = (bid >> 3) * 64;
        int n0 = h * 64;
        int rg = w >> 1, cg = w & 1;

        int arow = tid >> 3, achk = tid & 7;   // A staging: 64 rows x 8 chunks
        int bc = tid & 63, bjg = tid >> 6;     // B staging: 64 cols x 8 chunks

        const float* Xa = &X[(m0 + arow) * 512 + achk * 8];
        const float* Wb = &Wq[n0 + bc];

        float4 a0v, a1v;
        float bv[8], wvv[8];
        float tp = 0.f;
        f32x4 acc[2] = {{0.f,0.f,0.f,0.f},{0.f,0.f,0.f,0.f}};

#define LOADS(K0)                                                    \
        do {                                                         \
            a0v = *(const float4*)&Xa[(K0)];                         \
            a1v = *(const float4*)&Xa[(K0) + 4];                     \
            _Pragma("unroll")                                        \
            for (int i = 0; i < 8; ++i) {                            \
                bv[i]  = Wb[((K0) + bjg * 8 + i) * 512];             \
                wvv[i] = Wv[(K0) + bjg * 8 + i];                     \
            }                                                        \
        } while (0)

        LOADS(0);
        for (int k0 = 0; k0 < 512; k0 += 64) {
            __syncthreads();             // prev compute done reading LDS
            uint4 o;
            o.x = f2b(a0v.x) | (f2b(a0v.y) << 16);
            o.y = f2b(a0v.z) | (f2b(a0v.w) << 16);
            o.z = f2b(a1v.x) | (f2b(a1v.y) << 16);
            o.w = f2b(a1v.z) | (f2b(a1v.w) << 16);
            *(uint4*)&As[SWZ(arow, achk)] = o;
            o.x = f2b(bv[0]) | (f2b(bv[1]) << 16);
            o.y = f2b(bv[2]) | (f2b(bv[3]) << 16);
            o.z = f2b(bv[4]) | (f2b(bv[5]) << 16);
            o.w = f2b(bv[6]) | (f2b(bv[7]) << 16);
            *(uint4*)&Bs[SWZ(bc, bjg)] = o;
            #pragma unroll
            for (int i = 0; i < 8; ++i) tp = fmaf(bv[i], wvv[i], tp);
            __syncthreads();
            if (k0 < 448) LOADS(k0 + 64);   // next-tile loads overlap MFMAs
            int ar = rg * 16 + tt;
            bf16x8 fa0 = *(const bf16x8*)&As[SWZ(ar, quad)];
            bf16x8 fa1 = *(const bf16x8*)&As[SWZ(ar, quad + 4)];
            #pragma unroll
            for (int c = 0; c < 2; ++c) {
                int br = (cg * 2 + c) * 16 + tt;
                bf16x8 fb0 = *(const bf16x8*)&Bs[SWZ(br, quad)];
                bf16x8 fb1 = *(const bf16x8*)&Bs[SWZ(br, quad + 4)];
                acc[c] = __builtin_amdgcn_mfma_f32_16x16x32_bf16(fa0, fb0, acc[c], 0, 0, 0);
                acc[c] = __builtin_amdgcn_mfma_f32_16x16x32_bf16(fa1, fb1, acc[c], 0, 0, 0);
            }
        }

        tsh[bjg * 64 + bc] = tp;          // t[h] partials: 8 k-groups per col
        __syncthreads();
        float tv[2];
        #pragma unroll
        for (int c = 0; c < 2; ++c) {
            int col = (cg * 2 + c) * 16 + tt;
            float s = 0.f;
            #pragma unroll
            for (int j = 0; j < 8; ++j) s += tsh[j * 64 + col];
            tv[c] = s;
        }

        float s2[4] = {0.f,0.f,0.f,0.f}, yp[4] = {0.f,0.f,0.f,0.f};
        #pragma unroll
        for (int c = 0; c < 2; ++c)
            #pragma unroll
            for (int g = 0; g < 4; ++g) {
                float v = acc[c][g];
                s2[g] = fmaf(v, v, s2[g]);
                yp[g] = fmaf(v, tv[c], yp[g]);
                Qh[(m0 + rg * 16 + quad * 4 + g) * 512 + n0 + (cg * 2 + c) * 16 + tt] =
                    (unsigned short)f2b(v);
            }
        #pragma unroll
        for (int off = 1; off <= 8; off <<= 1)
            #pragma unroll
            for (int g = 0; g < 4; ++g) {
                s2[g] += __shfl_xor(s2[g], off);
                yp[g] += __shfl_xor(yp[g], off);
            }
        if (tt == 0) {
            #pragma unroll
            for (int g = 0; g < 4; ++g) {
                redS[cg][rg * 16 + quad * 4 + g] = s2[g];
                redY[cg][rg * 16 + quad * 4 + g] = yp[g];
            }
        }
        __syncthreads();
        if (tid < 64) {
            float s = redS[0][tid] + redS[1][tid];
            float y = redY[0][tid] + redY[1][tid];
            int bb = m0 >> 11;
            int idx = ((bb * 8 + h) << 11) + ((m0 + tid) & 2047);
            nl_ws[idx] = -C0125 * sqrtf(s);   // pre-scaled -0.125*log2e*n
            y_ws[idx] = y;
        }
    }

    // ---------------- Dependency barrier (device scope) ----------------
    {
        int g1 = (bid >> 8) * 8 + (bid & 7);   // this block produced (bb, h) rows
        int bh2 = bid >> 5;                    // this block will consume bh2
        __syncthreads();                       // all phase-1 stores issued+drained
        __threadfence();                       // release: writeback to coherence pt
        if (tid == 0) {
            atomicAdd(&cnt[g1 * CNT_STRIDE], 1u);
            // load-only poll (no RMW, no line ownership); padded counters
            while (__hip_atomic_load(&cnt[bh2 * CNT_STRIDE],
                                     __ATOMIC_RELAXED,
                                     __HIP_MEMORY_SCOPE_AGENT) < 32u)
                __builtin_amdgcn_s_sleep(2);
        }
        __syncthreads();
        __threadfence();                       // acquire: invalidate stale caches
    }

    // ---------------- Phase 2: attention ----------------
    {
        int bh = bid >> 5;              // 16 bh x 32 tiles
        int tile = bid & 31;
        int s0 = tile * 64;
        int b = bh >> 3, h = bh & 7;
        const unsigned short* Qb = Qh + (size_t)(b * 2048) * 512 + h * 64;
        const float* nb = nl_ws + bh * 2048;
        const float* yb = y_ws + bh * 2048;

        bf16x8 fa0[4], fa1[4];
        #pragma unroll
        for (int tl = 0; tl < 4; ++tl) {
            const unsigned short* r = &Qb[(size_t)(s0 + tl * 16 + tt) * 512];
            fa0[tl] = *(const bf16x8*)&r[quad * 8];
            fa1[tl] = *(const bf16x8*)&r[32 + quad * 8];
        }
        f32x4 num[4] = {{0.f,0.f,0.f,0.f},{0.f,0.f,0.f,0.f},
                        {0.f,0.f,0.f,0.f},{0.f,0.f,0.f,0.f}};
        f32x4 den[4] = {{0.f,0.f,0.f,0.f},{0.f,0.f,0.f,0.f},
                        {0.f,0.f,0.f,0.f},{0.f,0.f,0.f,0.f}};

        for (int st = 0; st < 16; ++st) {
            int tbase = w * 256 + st * 16;
            const unsigned short* rT = &Qb[(size_t)(tbase + tt) * 512];
            bf16x8 fb0 = *(const bf16x8*)&rT[quad * 8];
            bf16x8 fb1 = *(const bf16x8*)&rT[32 + quad * 8];
            float tqv = nb[tbase + tt];          // = -0.125*log2e*n_t
            float yv  = yb[tbase + tt];
            #pragma unroll
            for (int tl = 0; tl < 4; ++tl) {
                f32x4 dot = {0.f, 0.f, 0.f, 0.f};
                dot = __builtin_amdgcn_mfma_f32_16x16x32_bf16(fa0[tl], fb0, dot, 0, 0, 0);
                dot = __builtin_amdgcn_mfma_f32_16x16x32_bf16(fa1[tl], fb1, dot, 0, 0, 0);
                #pragma unroll
                for (int g = 0; g < 4; ++g) {
                    float arg = fmaf(C025, dot[g], tqv);
                    float e = EXP2F(arg);
                    num[tl][g] = fmaf(e, yv, num[tl][g]);
                    den[tl][g] += e;
                }
            }
        }

        #pragma unroll
        for (int off = 1; off <= 8; off <<= 1)
            #pragma unroll
            for (int tl = 0; tl < 4; ++tl)
                #pragma unroll
                for (int g = 0; g < 4; ++g) {
                    num[tl][g] += __shfl_xor(num[tl][g], off);
                    den[tl][g] += __shfl_xor(den[tl][g], off);
                }
        if (tt == 0) {
            #pragma unroll
            for (int tl = 0; tl < 4; ++tl)
                #pragma unroll
                for (int g = 0; g < 4; ++g) {
                    redN[w][tl * 16 + quad * 4 + g] = num[tl][g];
                    redD[w][tl * 16 + quad * 4 + g] = den[tl][g];
                }
        }
        __syncthreads();
        if (tid < 64) {
            float xn = 0.f, xd = 0.f;
            #pragma unroll
            for (int ww = 0; ww < 8; ++ww) {
                xn += redN[ww][tid];
                xd += redD[ww][tid];
            }
            float x = xn / xd;
            out[bh * 2048 + s0 + tid] = 1.0f / (1.0f + EXP2F(-x * LOG2E));
        }
    }
}

extern "C" void kernel_launch(void* const* d_in, const int* in_sizes, int n_in,
                              void* d_out, int out_size, void* d_ws, size_t ws_size,
                              hipStream_t stream) {
    const float* X  = (const float*)d_in[0];
    const float* Wq = (const float*)d_in[1];
    const float* Wv = (const float*)d_in[2];
    float* outp = (float*)d_out;
    float* ws = (float*)d_ws;

    float* nl_ws = ws;                                        // 32768 floats
    float* y_ws  = ws + 32768;                                // 32768 floats
    unsigned int* cnt_ws = (unsigned int*)(ws + 65536);       // 16 x 128B counters
    unsigned short* Qh_ws = (unsigned short*)(ws + 66048);    // 2M bf16 (16B-aligned)

    hipMemsetAsync(cnt_ws, 0, 16 * CNT_STRIDE * 4, stream);   // zero barrier counters
    fused_k<<<512, 512, 0, stream>>>(X, Wq, Wv, Qh_ws, nl_ws, y_ws, cnt_ws, outp);
}

// Round 6
// 124.679 us; speedup vs baseline: 2.1008x; 1.9781x over previous
//
#include <hip/hip_runtime.h>

// Problem: B=2, S=2048, D=512, H=8, dh=64.
// R9 = R8 with cache-maintenance cost fixed:
//   R7/R8 executed __threadfence() (agent fence -> per-XCD L2 writeback/inv
//   sweep) in ALL 512 threads x2 = 8192 serialized L2 sweeps -> ~190us idle.
//   R9: ONE release fence + ONE acquire fence per block (tid==0 only).
//   __syncthreads() already drains every wave's stores to L2; the sweep is
//   cache-wide, so a single wave's fence publishes/invalidates for the block.
// Structure unchanged:
//   Phase 1 (qgemm): Q = X @ Wq via bf16 MFMA, fp32->bf16 cast in registers,
//     swizzled LDS staging, next-tile loads under MFMAs. t[h] = Wh^T Wv
//     during B staging. Epilogue: Qh bf16, nl = -0.125*log2e*||Q||, y = Q.t.
//   Barrier: per-(b,h) padded counters; arrive atomicAdd; consumer
//     load-spins until 32. Co-residency guaranteed: 512 blocks = 2/CU x 256
//     CU (VGPR<=128, LDS 23.5KB) -> no deadlock.
//   Phase 2 (attn): out = sigmoid( softmax((2QQ^T - n_s - n_t)/8) @ y ).
//     Waves own disjoint t-ranges; B-frags from global (L2/L3-resident);
//     zero barriers in the main loop.

typedef __attribute__((ext_vector_type(8))) short bf16x8;
typedef __attribute__((ext_vector_type(4))) float f32x4;

#if __has_builtin(__builtin_amdgcn_exp2f)
#define EXP2F(x) __builtin_amdgcn_exp2f(x)
#else
#define EXP2F(x) exp2f(x)
#endif

#define LOG2E 1.44269504088896341f
#define C025  (0.25f * LOG2E)
#define C0125 (0.125f * LOG2E)

#define CNT_STRIDE 32   // 32 uints = 128 B per counter

__device__ inline unsigned int f2b(float f) {  // fp32 -> bf16 bits, RNE
    unsigned int u = __float_as_uint(f);
    return (u + 0x7fffu + ((u >> 16) & 1u)) >> 16;
}

// swizzled LDS tile: row stride 64 bf16 (128B), 16B chunk c at (c ^ (row&7))
#define SWZ(row, c) ((row) * 64 + (((c) ^ ((row) & 7)) * 8))

__global__ __launch_bounds__(512, 4) void fused_k(const float* __restrict__ X,
                                                  const float* __restrict__ Wq,
                                                  const float* __restrict__ Wv,
                                                  unsigned short* __restrict__ Qh,
                                                  float* __restrict__ nl_ws,
                                                  float* __restrict__ y_ws,
                                                  unsigned int* __restrict__ cnt,
                                                  float* __restrict__ out) {
    __shared__ __align__(16) unsigned short As[64 * 64];
    __shared__ __align__(16) unsigned short Bs[64 * 64];
    __shared__ float tsh[512];
    __shared__ float redS[2][64], redY[2][64];
    __shared__ float redN[8][64], redD[8][64];

    int tid = threadIdx.x;
    int bid = blockIdx.x;
    int w = tid >> 6, lane = tid & 63;
    int tt = lane & 15, quad = lane >> 4;

    // ---------------- Phase 1: Q-GEMM ----------------
    {
        int h = bid & 7;
        int m0 = (bid >> 3) * 64;
        int n0 = h * 64;
        int rg = w >> 1, cg = w & 1;

        int arow = tid >> 3, achk = tid & 7;   // A staging: 64 rows x 8 chunks
        int bc = tid & 63, bjg = tid >> 6;     // B staging: 64 cols x 8 chunks

        const float* Xa = &X[(m0 + arow) * 512 + achk * 8];
        const float* Wb = &Wq[n0 + bc];

        float4 a0v, a1v;
        float bv[8], wvv[8];
        float tp = 0.f;
        f32x4 acc[2] = {{0.f,0.f,0.f,0.f},{0.f,0.f,0.f,0.f}};

#define LOADS(K0)                                                    \
        do {                                                         \
            a0v = *(const float4*)&Xa[(K0)];                         \
            a1v = *(const float4*)&Xa[(K0) + 4];                     \
            _Pragma("unroll")                                        \
            for (int i = 0; i < 8; ++i) {                            \
                bv[i]  = Wb[((K0) + bjg * 8 + i) * 512];             \
                wvv[i] = Wv[(K0) + bjg * 8 + i];                     \
            }                                                        \
        } while (0)

        LOADS(0);
        for (int k0 = 0; k0 < 512; k0 += 64) {
            __syncthreads();             // prev compute done reading LDS
            uint4 o;
            o.x = f2b(a0v.x) | (f2b(a0v.y) << 16);
            o.y = f2b(a0v.z) | (f2b(a0v.w) << 16);
            o.z = f2b(a1v.x) | (f2b(a1v.y) << 16);
            o.w = f2b(a1v.z) | (f2b(a1v.w) << 16);
            *(uint4*)&As[SWZ(arow, achk)] = o;
            o.x = f2b(bv[0]) | (f2b(bv[1]) << 16);
            o.y = f2b(bv[2]) | (f2b(bv[3]) << 16);
            o.z = f2b(bv[4]) | (f2b(bv[5]) << 16);
            o.w = f2b(bv[6]) | (f2b(bv[7]) << 16);
            *(uint4*)&Bs[SWZ(bc, bjg)] = o;
            #pragma unroll
            for (int i = 0; i < 8; ++i) tp = fmaf(bv[i], wvv[i], tp);
            __syncthreads();
            if (k0 < 448) LOADS(k0 + 64);   // next-tile loads overlap MFMAs
            int ar = rg * 16 + tt;
            bf16x8 fa0 = *(const bf16x8*)&As[SWZ(ar, quad)];
            bf16x8 fa1 = *(const bf16x8*)&As[SWZ(ar, quad + 4)];
            #pragma unroll
            for (int c = 0; c < 2; ++c) {
                int br = (cg * 2 + c) * 16 + tt;
                bf16x8 fb0 = *(const bf16x8*)&Bs[SWZ(br, quad)];
                bf16x8 fb1 = *(const bf16x8*)&Bs[SWZ(br, quad + 4)];
                acc[c] = __builtin_amdgcn_mfma_f32_16x16x32_bf16(fa0, fb0, acc[c], 0, 0, 0);
                acc[c] = __builtin_amdgcn_mfma_f32_16x16x32_bf16(fa1, fb1, acc[c], 0, 0, 0);
            }
        }

        tsh[bjg * 64 + bc] = tp;          // t[h] partials: 8 k-groups per col
        __syncthreads();
        float tv[2];
        #pragma unroll
        for (int c = 0; c < 2; ++c) {
            int col = (cg * 2 + c) * 16 + tt;
            float s = 0.f;
            #pragma unroll
            for (int j = 0; j < 8; ++j) s += tsh[j * 64 + col];
            tv[c] = s;
        }

        float s2[4] = {0.f,0.f,0.f,0.f}, yp[4] = {0.f,0.f,0.f,0.f};
        #pragma unroll
        for (int c = 0; c < 2; ++c)
            #pragma unroll
            for (int g = 0; g < 4; ++g) {
                float v = acc[c][g];
                s2[g] = fmaf(v, v, s2[g]);
                yp[g] = fmaf(v, tv[c], yp[g]);
                Qh[(m0 + rg * 16 + quad * 4 + g) * 512 + n0 + (cg * 2 + c) * 16 + tt] =
                    (unsigned short)f2b(v);
            }
        #pragma unroll
        for (int off = 1; off <= 8; off <<= 1)
            #pragma unroll
            for (int g = 0; g < 4; ++g) {
                s2[g] += __shfl_xor(s2[g], off);
                yp[g] += __shfl_xor(yp[g], off);
            }
        if (tt == 0) {
            #pragma unroll
            for (int g = 0; g < 4; ++g) {
                redS[cg][rg * 16 + quad * 4 + g] = s2[g];
                redY[cg][rg * 16 + quad * 4 + g] = yp[g];
            }
        }
        __syncthreads();
        if (tid < 64) {
            float s = redS[0][tid] + redS[1][tid];
            float y = redY[0][tid] + redY[1][tid];
            int bb = m0 >> 11;
            int idx = ((bb * 8 + h) << 11) + ((m0 + tid) & 2047);
            nl_ws[idx] = -C0125 * sqrtf(s);   // pre-scaled -0.125*log2e*n
            y_ws[idx] = y;
        }
    }

    // ---------------- Dependency barrier (device scope) ----------------
    {
        int g1 = (bid >> 8) * 8 + (bid & 7);   // this block produced (bb, h) rows
        int bh2 = bid >> 5;                    // this block will consume bh2
        __syncthreads();                       // all waves' stores complete in L2
        if (tid == 0) {
            __threadfence();                   // ONE release sweep per block
            atomicAdd(&cnt[g1 * CNT_STRIDE], 1u);
            while (__hip_atomic_load(&cnt[bh2 * CNT_STRIDE],
                                     __ATOMIC_RELAXED,
                                     __HIP_MEMORY_SCOPE_AGENT) < 32u)
                __builtin_amdgcn_s_sleep(2);
            __threadfence();                   // ONE acquire sweep per block
        }
        __syncthreads();                       // release other waves; loads can't hoist
    }

    // ---------------- Phase 2: attention ----------------
    {
        int bh = bid >> 5;              // 16 bh x 32 tiles
        int tile = bid & 31;
        int s0 = tile * 64;
        int b = bh >> 3, h = bh & 7;
        const unsigned short* Qb = Qh + (size_t)(b * 2048) * 512 + h * 64;
        const float* nb = nl_ws + bh * 2048;
        const float* yb = y_ws + bh * 2048;

        bf16x8 fa0[4], fa1[4];
        #pragma unroll
        for (int tl = 0; tl < 4; ++tl) {
            const unsigned short* r = &Qb[(size_t)(s0 + tl * 16 + tt) * 512];
            fa0[tl] = *(const bf16x8*)&r[quad * 8];
            fa1[tl] = *(const bf16x8*)&r[32 + quad * 8];
        }
        f32x4 num[4] = {{0.f,0.f,0.f,0.f},{0.f,0.f,0.f,0.f},
                        {0.f,0.f,0.f,0.f},{0.f,0.f,0.f,0.f}};
        f32x4 den[4] = {{0.f,0.f,0.f,0.f},{0.f,0.f,0.f,0.f},
                        {0.f,0.f,0.f,0.f},{0.f,0.f,0.f,0.f}};

        for (int st = 0; st < 16; ++st) {
            int tbase = w * 256 + st * 16;
            const unsigned short* rT = &Qb[(size_t)(tbase + tt) * 512];
            bf16x8 fb0 = *(const bf16x8*)&rT[quad * 8];
            bf16x8 fb1 = *(const bf16x8*)&rT[32 + quad * 8];
            float tqv = nb[tbase + tt];          // = -0.125*log2e*n_t
            float yv  = yb[tbase + tt];
            #pragma unroll
            for (int tl = 0; tl < 4; ++tl) {
                f32x4 dot = {0.f, 0.f, 0.f, 0.f};
                dot = __builtin_amdgcn_mfma_f32_16x16x32_bf16(fa0[tl], fb0, dot, 0, 0, 0);
                dot = __builtin_amdgcn_mfma_f32_16x16x32_bf16(fa1[tl], fb1, dot, 0, 0, 0);
                #pragma unroll
                for (int g = 0; g < 4; ++g) {
                    float arg = fmaf(C025, dot[g], tqv);
                    float e = EXP2F(arg);
                    num[tl][g] = fmaf(e, yv, num[tl][g]);
                    den[tl][g] += e;
                }
            }
        }

        #pragma unroll
        for (int off = 1; off <= 8; off <<= 1)
            #pragma unroll
            for (int tl = 0; tl < 4; ++tl)
                #pragma unroll
                for (int g = 0; g < 4; ++g) {
                    num[tl][g] += __shfl_xor(num[tl][g], off);
                    den[tl][g] += __shfl_xor(den[tl][g], off);
                }
        if (tt == 0) {
            #pragma unroll
            for (int tl = 0; tl < 4; ++tl)
                #pragma unroll
                for (int g = 0; g < 4; ++g) {
                    redN[w][tl * 16 + quad * 4 + g] = num[tl][g];
                    redD[w][tl * 16 + quad * 4 + g] = den[tl][g];
                }
        }
        __syncthreads();
        if (tid < 64) {
            float xn = 0.f, xd = 0.f;
            #pragma unroll
            for (int ww = 0; ww < 8; ++ww) {
                xn += redN[ww][tid];
                xd += redD[ww][tid];
            }
            float x = xn / xd;
            out[bh * 2048 + s0 + tid] = 1.0f / (1.0f + EXP2F(-x * LOG2E));
        }
    }
}

extern "C" void kernel_launch(void* const* d_in, const int* in_sizes, int n_in,
                              void* d_out, int out_size, void* d_ws, size_t ws_size,
                              hipStream_t stream) {
    const float* X  = (const float*)d_in[0];
    const float* Wq = (const float*)d_in[1];
    const float* Wv = (const float*)d_in[2];
    float* outp = (float*)d_out;
    float* ws = (float*)d_ws;

    float* nl_ws = ws;                                        // 32768 floats
    float* y_ws  = ws + 32768;                                // 32768 floats
    unsigned int* cnt_ws = (unsigned int*)(ws + 65536);       // 16 x 128B counters
    unsigned short* Qh_ws = (unsigned short*)(ws + 66048);    // 2M bf16 (16B-aligned)

    hipMemsetAsync(cnt_ws, 0, 16 * CNT_STRIDE * 4, stream);   // zero barrier counters
    fused_k<<<512, 512, 0, stream>>>(X, Wq, Wv, Qh_ws, nl_ws, y_ws, cnt_ws, outp);
}

// Round 7
// 122.364 us; speedup vs baseline: 2.1406x; 1.0189x over previous
//
#include <hip/hip_runtime.h>

// Problem: B=2, S=2048, D=512, H=8, dh=64.
// R10 = R9 with ALL cache-maintenance removed (scoped ops instead of fences):
//   R9 still did 1024 L2 sweeps (wbl2+inv per block); the 512 acquire
//   invalidates continuously nuked per-XCD L2 during phase 2 (FETCH 51MB vs
//   9MB compulsory). R10: phase-1 results stored with AGENT-scope
//   write-through stores (via LDS repack to 8B lanes); phase-2 reads them
//   with AGENT-scope loads (bypass L1/L2, always coherent). Arrival is a
//   RELEASE fetch_add; spin is a RELAXED load. No __threadfence anywhere.
// Structure unchanged:
//   Phase 1 (qgemm): Q = X @ Wq via bf16 MFMA, fp32->bf16 cast in registers,
//     swizzled LDS staging, next-tile loads under MFMAs. t[h] = Wh^T Wv
//     during B staging. Epilogue: Qh bf16, nl = -0.125*log2e*||Q||, y = Q.t.
//   Barrier: per-(b,h) padded counters; co-residency guaranteed:
//     512 blocks = 2/CU x 256 CU (VGPR<=128, LDS 23.5KB) -> no deadlock.
//   Phase 2 (attn): out = sigmoid( softmax((2QQ^T - n_s - n_t)/8) @ y ).
//     Waves own disjoint t-ranges; zero barriers in the main loop.

typedef __attribute__((ext_vector_type(8))) short bf16x8;
typedef __attribute__((ext_vector_type(4))) float f32x4;

#if __has_builtin(__builtin_amdgcn_exp2f)
#define EXP2F(x) __builtin_amdgcn_exp2f(x)
#else
#define EXP2F(x) exp2f(x)
#endif

#define LOG2E 1.44269504088896341f
#define C025  (0.25f * LOG2E)
#define C0125 (0.125f * LOG2E)

#define CNT_STRIDE 32   // 32 uints = 128 B per counter

__device__ inline unsigned int f2b(float f) {  // fp32 -> bf16 bits, RNE
    unsigned int u = __float_as_uint(f);
    return (u + 0x7fffu + ((u >> 16) & 1u)) >> 16;
}

// agent-scope coherent 16B load (2x8B, bypasses L1/L2 -> coherence point)
__device__ __forceinline__ bf16x8 ald16(const unsigned short* p) {
    union { unsigned long long q[2]; bf16x8 v; } u;
    u.q[0] = __hip_atomic_load((const unsigned long long*)p,
                               __ATOMIC_RELAXED, __HIP_MEMORY_SCOPE_AGENT);
    u.q[1] = __hip_atomic_load((const unsigned long long*)(p + 4),
                               __ATOMIC_RELAXED, __HIP_MEMORY_SCOPE_AGENT);
    return u.v;
}

__device__ __forceinline__ float aldf(const float* p) {
    return __hip_atomic_load(p, __ATOMIC_RELAXED, __HIP_MEMORY_SCOPE_AGENT);
}

// swizzled LDS tile: row stride 64 bf16 (128B), 16B chunk c at (c ^ (row&7))
#define SWZ(row, c) ((row) * 64 + (((c) ^ ((row) & 7)) * 8))

__global__ __launch_bounds__(512, 4) void fused_k(const float* __restrict__ X,
                                                  const float* __restrict__ Wq,
                                                  const float* __restrict__ Wv,
                                                  unsigned short* __restrict__ Qh,
                                                  float* __restrict__ nl_ws,
                                                  float* __restrict__ y_ws,
                                                  unsigned int* __restrict__ cnt,
                                                  float* __restrict__ out) {
    __shared__ __align__(16) unsigned short As[64 * 64];
    __shared__ __align__(16) unsigned short Bs[64 * 64];
    __shared__ float tsh[512];
    __shared__ float redS[2][64], redY[2][64];
    __shared__ float redN[8][64], redD[8][64];

    int tid = threadIdx.x;
    int bid = blockIdx.x;
    int w = tid >> 6, lane = tid & 63;
    int tt = lane & 15, quad = lane >> 4;

    // ---------------- Phase 1: Q-GEMM ----------------
    {
        int h = bid & 7;
        int m0 = (bid >> 3) * 64;
        int n0 = h * 64;
        int rg = w >> 1, cg = w & 1;

        int arow = tid >> 3, achk = tid & 7;   // A staging: 64 rows x 8 chunks
        int bc = tid & 63, bjg = tid >> 6;     // B staging: 64 cols x 8 chunks

        const float* Xa = &X[(m0 + arow) * 512 + achk * 8];
        const float* Wb = &Wq[n0 + bc];

        float4 a0v, a1v;
        float bv[8], wvv[8];
        float tp = 0.f;
        f32x4 acc[2] = {{0.f,0.f,0.f,0.f},{0.f,0.f,0.f,0.f}};

#define LOADS(K0)                                                    \
        do {                                                         \
            a0v = *(const float4*)&Xa[(K0)];                         \
            a1v = *(const float4*)&Xa[(K0) + 4];                     \
            _Pragma("unroll")                                        \
            for (int i = 0; i < 8; ++i) {                            \
                bv[i]  = Wb[((K0) + bjg * 8 + i) * 512];             \
                wvv[i] = Wv[(K0) + bjg * 8 + i];                     \
            }                                                        \
        } while (0)

        LOADS(0);
        for (int k0 = 0; k0 < 512; k0 += 64) {
            __syncthreads();             // prev compute done reading LDS
            uint4 o;
            o.x = f2b(a0v.x) | (f2b(a0v.y) << 16);
            o.y = f2b(a0v.z) | (f2b(a0v.w) << 16);
            o.z = f2b(a1v.x) | (f2b(a1v.y) << 16);
            o.w = f2b(a1v.z) | (f2b(a1v.w) << 16);
            *(uint4*)&As[SWZ(arow, achk)] = o;
            o.x = f2b(bv[0]) | (f2b(bv[1]) << 16);
            o.y = f2b(bv[2]) | (f2b(bv[3]) << 16);
            o.z = f2b(bv[4]) | (f2b(bv[5]) << 16);
            o.w = f2b(bv[6]) | (f2b(bv[7]) << 16);
            *(uint4*)&Bs[SWZ(bc, bjg)] = o;
            #pragma unroll
            for (int i = 0; i < 8; ++i) tp = fmaf(bv[i], wvv[i], tp);
            __syncthreads();
            if (k0 < 448) LOADS(k0 + 64);   // next-tile loads overlap MFMAs
            int ar = rg * 16 + tt;
            bf16x8 fa0 = *(const bf16x8*)&As[SWZ(ar, quad)];
            bf16x8 fa1 = *(const bf16x8*)&As[SWZ(ar, quad + 4)];
            #pragma unroll
            for (int c = 0; c < 2; ++c) {
                int br = (cg * 2 + c) * 16 + tt;
                bf16x8 fb0 = *(const bf16x8*)&Bs[SWZ(br, quad)];
                bf16x8 fb1 = *(const bf16x8*)&Bs[SWZ(br, quad + 4)];
                acc[c] = __builtin_amdgcn_mfma_f32_16x16x32_bf16(fa0, fb0, acc[c], 0, 0, 0);
                acc[c] = __builtin_amdgcn_mfma_f32_16x16x32_bf16(fa1, fb1, acc[c], 0, 0, 0);
            }
        }

        tsh[bjg * 64 + bc] = tp;          // t[h] partials: 8 k-groups per col
        __syncthreads();                  // also: all As/Bs reads complete
        float tv[2];
        #pragma unroll
        for (int c = 0; c < 2; ++c) {
            int col = (cg * 2 + c) * 16 + tt;
            float s = 0.f;
            #pragma unroll
            for (int j = 0; j < 8; ++j) s += tsh[j * 64 + col];
            tv[c] = s;
        }

        // epilogue: n/y partials; repack Q tile into As (linear [row][col])
        float s2[4] = {0.f,0.f,0.f,0.f}, yp[4] = {0.f,0.f,0.f,0.f};
        #pragma unroll
        for (int c = 0; c < 2; ++c)
            #pragma unroll
            for (int g = 0; g < 4; ++g) {
                float v = acc[c][g];
                s2[g] = fmaf(v, v, s2[g]);
                yp[g] = fmaf(v, tv[c], yp[g]);
                As[(rg * 16 + quad * 4 + g) * 64 + (cg * 2 + c) * 16 + tt] =
                    (unsigned short)f2b(v);
            }
        #pragma unroll
        for (int off = 1; off <= 8; off <<= 1)
            #pragma unroll
            for (int g = 0; g < 4; ++g) {
                s2[g] += __shfl_xor(s2[g], off);
                yp[g] += __shfl_xor(yp[g], off);
            }
        if (tt == 0) {
            #pragma unroll
            for (int g = 0; g < 4; ++g) {
                redS[cg][rg * 16 + quad * 4 + g] = s2[g];
                redY[cg][rg * 16 + quad * 4 + g] = yp[g];
            }
        }
        __syncthreads();                  // As repack + redS/redY visible
        if (tid < 64) {
            float s = redS[0][tid] + redS[1][tid];
            float y = redY[0][tid] + redY[1][tid];
            int bb = m0 >> 11;
            int idx = ((bb * 8 + h) << 11) + ((m0 + tid) & 2047);
            __hip_atomic_store(&nl_ws[idx], -C0125 * sqrtf(s),
                               __ATOMIC_RELAXED, __HIP_MEMORY_SCOPE_AGENT);
            __hip_atomic_store(&y_ws[idx], y,
                               __ATOMIC_RELAXED, __HIP_MEMORY_SCOPE_AGENT);
        }
        {   // Qh store: 16B/thread from linear As, agent write-through (2x8B)
            const unsigned long long* lp = (const unsigned long long*)As;
            unsigned long long q0 = lp[tid * 2];
            unsigned long long q1 = lp[tid * 2 + 1];
            int row = tid >> 3, col = (tid & 7) * 8;
            unsigned long long* gp =
                (unsigned long long*)&Qh[(size_t)(m0 + row) * 512 + n0 + col];
            __hip_atomic_store(&gp[0], q0, __ATOMIC_RELAXED, __HIP_MEMORY_SCOPE_AGENT);
            __hip_atomic_store(&gp[1], q1, __ATOMIC_RELAXED, __HIP_MEMORY_SCOPE_AGENT);
        }
    }

    // ---------------- Dependency barrier (scoped, no fences) ----------------
    {
        int g1 = (bid >> 8) * 8 + (bid & 7);   // this block produced (bb, h) rows
        int bh2 = bid >> 5;                    // this block will consume bh2
        __syncthreads();                       // all agent stores issued by block
        if (tid == 0) {
            __hip_atomic_fetch_add(&cnt[g1 * CNT_STRIDE], 1u,
                                   __ATOMIC_RELEASE, __HIP_MEMORY_SCOPE_AGENT);
            while (__hip_atomic_load(&cnt[bh2 * CNT_STRIDE],
                                     __ATOMIC_RELAXED,
                                     __HIP_MEMORY_SCOPE_AGENT) < 32u)
                __builtin_amdgcn_s_sleep(2);
        }
        __syncthreads();                       // consumers held until ready
    }

    // ---------------- Phase 2: attention ----------------
    {
        int bh = bid >> 5;              // 16 bh x 32 tiles
        int tile = bid & 31;
        int s0 = tile * 64;
        int b = bh >> 3, h = bh & 7;
        const unsigned short* Qb = Qh + (size_t)(b * 2048) * 512 + h * 64;
        const float* nb = nl_ws + bh * 2048;
        const float* yb = y_ws + bh * 2048;

        bf16x8 fa0[4], fa1[4];
        #pragma unroll
        for (int tl = 0; tl < 4; ++tl) {
            const unsigned short* r = &Qb[(size_t)(s0 + tl * 16 + tt) * 512];
            fa0[tl] = ald16(&r[quad * 8]);
            fa1[tl] = ald16(&r[32 + quad * 8]);
        }
        f32x4 num[4] = {{0.f,0.f,0.f,0.f},{0.f,0.f,0.f,0.f},
                        {0.f,0.f,0.f,0.f},{0.f,0.f,0.f,0.f}};
        f32x4 den[4] = {{0.f,0.f,0.f,0.f},{0.f,0.f,0.f,0.f},
                        {0.f,0.f,0.f,0.f},{0.f,0.f,0.f,0.f}};

        for (int st = 0; st < 16; ++st) {
            int tbase = w * 256 + st * 16;
            const unsigned short* rT = &Qb[(size_t)(tbase + tt) * 512];
            bf16x8 fb0 = ald16(&rT[quad * 8]);
            bf16x8 fb1 = ald16(&rT[32 + quad * 8]);
            float tqv = aldf(&nb[tbase + tt]);   // = -0.125*log2e*n_t
            float yv  = aldf(&yb[tbase + tt]);
            #pragma unroll
            for (int tl = 0; tl < 4; ++tl) {
                f32x4 dot = {0.f, 0.f, 0.f, 0.f};
                dot = __builtin_amdgcn_mfma_f32_16x16x32_bf16(fa0[tl], fb0, dot, 0, 0, 0);
                dot = __builtin_amdgcn_mfma_f32_16x16x32_bf16(fa1[tl], fb1, dot, 0, 0, 0);
                #pragma unroll
                for (int g = 0; g < 4; ++g) {
                    float arg = fmaf(C025, dot[g], tqv);
                    float e = EXP2F(arg);
                    num[tl][g] = fmaf(e, yv, num[tl][g]);
                    den[tl][g] += e;
                }
            }
        }

        #pragma unroll
        for (int off = 1; off <= 8; off <<= 1)
            #pragma unroll
            for (int tl = 0; tl < 4; ++tl)
                #pragma unroll
                for (int g = 0; g < 4; ++g) {
                    num[tl][g] += __shfl_xor(num[tl][g], off);
                    den[tl][g] += __shfl_xor(den[tl][g], off);
                }
        if (tt == 0) {
            #pragma unroll
            for (int tl = 0; tl < 4; ++tl)
                #pragma unroll
                for (int g = 0; g < 4; ++g) {
                    redN[w][tl * 16 + quad * 4 + g] = num[tl][g];
                    redD[w][tl * 16 + quad * 4 + g] = den[tl][g];
                }
        }
        __syncthreads();
        if (tid < 64) {
            float xn = 0.f, xd = 0.f;
            #pragma unroll
            for (int ww = 0; ww < 8; ++ww) {
                xn += redN[ww][tid];
                xd += redD[ww][tid];
            }
            float x = xn / xd;
            out[bh * 2048 + s0 + tid] = 1.0f / (1.0f + EXP2F(-x * LOG2E));
        }
    }
}

extern "C" void kernel_launch(void* const* d_in, const int* in_sizes, int n_in,
                              void* d_out, int out_size, void* d_ws, size_t ws_size,
                              hipStream_t stream) {
    const float* X  = (const float*)d_in[0];
    const float* Wq = (const float*)d_in[1];
    const float* Wv = (const float*)d_in[2];
    float* outp = (float*)d_out;
    float* ws = (float*)d_ws;

    float* nl_ws = ws;                                        // 32768 floats
    float* y_ws  = ws + 32768;                                // 32768 floats
    unsigned int* cnt_ws = (unsigned int*)(ws + 65536);       // 16 x 128B counters
    unsigned short* Qh_ws = (unsigned short*)(ws + 66048);    // 2M bf16 (16B-aligned)

    hipMemsetAsync(cnt_ws, 0, 16 * CNT_STRIDE * 4, stream);   // zero barrier counters
    fused_k<<<512, 512, 0, stream>>>(X, Wq, Wv, Qh_ws, nl_ws, y_ws, cnt_ws, outp);
}

// Round 8
// 101.594 us; speedup vs baseline: 2.5782x; 1.2045x over previous
//
#include <hip/hip_runtime.h>

// Problem: B=2, S=2048, D=512, H=8, dh=64.
// R11 = R10 with the REAL bottleneck fixed: memory locality, not coherence.
//   R9/R10 both sat at 70us: X row-panels were fetched ~8x (sharing blocks on
//   different XCDs) and phase-2 Qh reads were L2-miss-always (agent-scope /
//   invalidate-harassed) and non-pipelinable (atomic loads). R11:
//   (1) producer map h=bid>>6, m0=(bid&63)*64 -> X-panel sharers on SAME XCD;
//   (2) consumer map bh=bid&15, tile=bid>>4 -> all 32 blocks of a bh on SAME
//       XCD, Qh slice fetched once then L2-hit;
//   (3) phase 2 uses PLAIN cached loads + manual prefetch. Safe because:
//       kernel-start acquire invalidates L2 (validated by 2-kernel R5),
//       producers write Qh/nl/y write-through agent-scope (nothing dirty),
//       consumers read only after the counter barrier.
//   Barrier unchanged from R10 (release fetch_add, relaxed load spin).
//   Co-residency: 512 blocks = 2/CU x 256 CU (VGPR<=128, LDS 23.5KB).

typedef __attribute__((ext_vector_type(8))) short bf16x8;
typedef __attribute__((ext_vector_type(4))) float f32x4;

#if __has_builtin(__builtin_amdgcn_exp2f)
#define EXP2F(x) __builtin_amdgcn_exp2f(x)
#else
#define EXP2F(x) exp2f(x)
#endif

#define LOG2E 1.44269504088896341f
#define C025  (0.25f * LOG2E)
#define C0125 (0.125f * LOG2E)

#define CNT_STRIDE 32   // 32 uints = 128 B per counter

__device__ inline unsigned int f2b(float f) {  // fp32 -> bf16 bits, RNE
    unsigned int u = __float_as_uint(f);
    return (u + 0x7fffu + ((u >> 16) & 1u)) >> 16;
}

// swizzled LDS tile: row stride 64 bf16 (128B), 16B chunk c at (c ^ (row&7))
#define SWZ(row, c) ((row) * 64 + (((c) ^ ((row) & 7)) * 8))

__global__ __launch_bounds__(512, 4) void fused_k(const float* __restrict__ X,
                                                  const float* __restrict__ Wq,
                                                  const float* __restrict__ Wv,
                                                  unsigned short* __restrict__ Qh,
                                                  float* __restrict__ nl_ws,
                                                  float* __restrict__ y_ws,
                                                  unsigned int* __restrict__ cnt,
                                                  float* __restrict__ out) {
    __shared__ __align__(16) unsigned short As[64 * 64];
    __shared__ __align__(16) unsigned short Bs[64 * 64];
    __shared__ float tsh[512];
    __shared__ float redS[2][64], redY[2][64];
    __shared__ float redN[8][64], redD[8][64];

    int tid = threadIdx.x;
    int bid = blockIdx.x;
    int w = tid >> 6, lane = tid & 63;
    int tt = lane & 15, quad = lane >> 4;

    // ---------------- Phase 1: Q-GEMM ----------------
    {
        int h = bid >> 6;                  // XCD-local X panels: same-m0 blocks
        int m0 = (bid & 63) * 64;          // share bid%8 -> same XCD L2
        int n0 = h * 64;
        int rg = w >> 1, cg = w & 1;

        int arow = tid >> 3, achk = tid & 7;   // A staging: 64 rows x 8 chunks
        int bc = tid & 63, bjg = tid >> 6;     // B staging: 64 cols x 8 chunks

        const float* Xa = &X[(m0 + arow) * 512 + achk * 8];
        const float* Wb = &Wq[n0 + bc];

        float4 a0v, a1v;
        float bv[8], wvv[8];
        float tp = 0.f;
        f32x4 acc[2] = {{0.f,0.f,0.f,0.f},{0.f,0.f,0.f,0.f}};

#define LOADS(K0)                                                    \
        do {                                                         \
            a0v = *(const float4*)&Xa[(K0)];                         \
            a1v = *(const float4*)&Xa[(K0) + 4];                     \
            _Pragma("unroll")                                        \
            for (int i = 0; i < 8; ++i) {                            \
                bv[i]  = Wb[((K0) + bjg * 8 + i) * 512];             \
                wvv[i] = Wv[(K0) + bjg * 8 + i];                     \
            }                                                        \
        } while (0)

        LOADS(0);
        for (int k0 = 0; k0 < 512; k0 += 64) {
            __syncthreads();             // prev compute done reading LDS
            uint4 o;
            o.x = f2b(a0v.x) | (f2b(a0v.y) << 16);
            o.y = f2b(a0v.z) | (f2b(a0v.w) << 16);
            o.z = f2b(a1v.x) | (f2b(a1v.y) << 16);
            o.w = f2b(a1v.z) | (f2b(a1v.w) << 16);
            *(uint4*)&As[SWZ(arow, achk)] = o;
            o.x = f2b(bv[0]) | (f2b(bv[1]) << 16);
            o.y = f2b(bv[2]) | (f2b(bv[3]) << 16);
            o.z = f2b(bv[4]) | (f2b(bv[5]) << 16);
            o.w = f2b(bv[6]) | (f2b(bv[7]) << 16);
            *(uint4*)&Bs[SWZ(bc, bjg)] = o;
            #pragma unroll
            for (int i = 0; i < 8; ++i) tp = fmaf(bv[i], wvv[i], tp);
            __syncthreads();
            if (k0 < 448) LOADS(k0 + 64);   // next-tile loads overlap MFMAs
            int ar = rg * 16 + tt;
            bf16x8 fa0 = *(const bf16x8*)&As[SWZ(ar, quad)];
            bf16x8 fa1 = *(const bf16x8*)&As[SWZ(ar, quad + 4)];
            #pragma unroll
            for (int c = 0; c < 2; ++c) {
                int br = (cg * 2 + c) * 16 + tt;
                bf16x8 fb0 = *(const bf16x8*)&Bs[SWZ(br, quad)];
                bf16x8 fb1 = *(const bf16x8*)&Bs[SWZ(br, quad + 4)];
                acc[c] = __builtin_amdgcn_mfma_f32_16x16x32_bf16(fa0, fb0, acc[c], 0, 0, 0);
                acc[c] = __builtin_amdgcn_mfma_f32_16x16x32_bf16(fa1, fb1, acc[c], 0, 0, 0);
            }
        }

        tsh[bjg * 64 + bc] = tp;          // t[h] partials: 8 k-groups per col
        __syncthreads();                  // also: all As/Bs reads complete
        float tv[2];
        #pragma unroll
        for (int c = 0; c < 2; ++c) {
            int col = (cg * 2 + c) * 16 + tt;
            float s = 0.f;
            #pragma unroll
            for (int j = 0; j < 8; ++j) s += tsh[j * 64 + col];
            tv[c] = s;
        }

        // epilogue: n/y partials; repack Q tile into As (linear [row][col])
        float s2[4] = {0.f,0.f,0.f,0.f}, yp[4] = {0.f,0.f,0.f,0.f};
        #pragma unroll
        for (int c = 0; c < 2; ++c)
            #pragma unroll
            for (int g = 0; g < 4; ++g) {
                float v = acc[c][g];
                s2[g] = fmaf(v, v, s2[g]);
                yp[g] = fmaf(v, tv[c], yp[g]);
                As[(rg * 16 + quad * 4 + g) * 64 + (cg * 2 + c) * 16 + tt] =
                    (unsigned short)f2b(v);
            }
        #pragma unroll
        for (int off = 1; off <= 8; off <<= 1)
            #pragma unroll
            for (int g = 0; g < 4; ++g) {
                s2[g] += __shfl_xor(s2[g], off);
                yp[g] += __shfl_xor(yp[g], off);
            }
        if (tt == 0) {
            #pragma unroll
            for (int g = 0; g < 4; ++g) {
                redS[cg][rg * 16 + quad * 4 + g] = s2[g];
                redY[cg][rg * 16 + quad * 4 + g] = yp[g];
            }
        }
        __syncthreads();                  // As repack + redS/redY visible
        if (tid < 64) {
            float s = redS[0][tid] + redS[1][tid];
            float y = redY[0][tid] + redY[1][tid];
            int bb = m0 >> 11;
            int idx = ((bb * 8 + h) << 11) + ((m0 + tid) & 2047);
            __hip_atomic_store(&nl_ws[idx], -C0125 * sqrtf(s),
                               __ATOMIC_RELAXED, __HIP_MEMORY_SCOPE_AGENT);
            __hip_atomic_store(&y_ws[idx], y,
                               __ATOMIC_RELAXED, __HIP_MEMORY_SCOPE_AGENT);
        }
        {   // Qh store: 16B/thread from linear As, agent write-through (2x8B)
            const unsigned long long* lp = (const unsigned long long*)As;
            unsigned long long q0 = lp[tid * 2];
            unsigned long long q1 = lp[tid * 2 + 1];
            int row = tid >> 3, col = (tid & 7) * 8;
            unsigned long long* gp =
                (unsigned long long*)&Qh[(size_t)(m0 + row) * 512 + n0 + col];
            __hip_atomic_store(&gp[0], q0, __ATOMIC_RELAXED, __HIP_MEMORY_SCOPE_AGENT);
            __hip_atomic_store(&gp[1], q1, __ATOMIC_RELAXED, __HIP_MEMORY_SCOPE_AGENT);
        }
    }

    // ---------------- Dependency barrier (scoped, no fences) ----------------
    {
        int g1 = ((bid & 63) >> 5) * 8 + (bid >> 6);   // (bb, h) this block produced
        int bh2 = bid & 15;                            // bh this block will consume
        __syncthreads();                       // all agent stores complete (vmcnt 0)
        if (tid == 0) {
            __hip_atomic_fetch_add(&cnt[g1 * CNT_STRIDE], 1u,
                                   __ATOMIC_RELEASE, __HIP_MEMORY_SCOPE_AGENT);
            while (__hip_atomic_load(&cnt[bh2 * CNT_STRIDE],
                                     __ATOMIC_RELAXED,
                                     __HIP_MEMORY_SCOPE_AGENT) < 32u)
                __builtin_amdgcn_s_sleep(2);
        }
        __syncthreads();                       // consumers held until ready
    }

    // ---------------- Phase 2: attention ----------------
    {
        int bh = bid & 15;              // all 32 blocks of bh share bid%8 -> XCD
        int tile = bid >> 4;
        int s0 = tile * 64;
        int b = bh >> 3, h = bh & 7;
        const unsigned short* __restrict__ Qb =
            Qh + (size_t)(b * 2048) * 512 + h * 64;
        const float* __restrict__ nb = nl_ws + bh * 2048;
        const float* __restrict__ yb = y_ws + bh * 2048;

        bf16x8 fa0[4], fa1[4];
        #pragma unroll
        for (int tl = 0; tl < 4; ++tl) {
            const unsigned short* r = &Qb[(size_t)(s0 + tl * 16 + tt) * 512];
            fa0[tl] = *(const bf16x8*)&r[quad * 8];
            fa1[tl] = *(const bf16x8*)&r[32 + quad * 8];
        }
        f32x4 num[4] = {{0.f,0.f,0.f,0.f},{0.f,0.f,0.f,0.f},
                        {0.f,0.f,0.f,0.f},{0.f,0.f,0.f,0.f}};
        f32x4 den[4] = {{0.f,0.f,0.f,0.f},{0.f,0.f,0.f,0.f},
                        {0.f,0.f,0.f,0.f},{0.f,0.f,0.f,0.f}};

        // wave's t-range [w*256, w*256+256), manual 1-deep prefetch pipeline
        const unsigned short* rT = &Qb[(size_t)(w * 256 + tt) * 512];
        bf16x8 fb0c = *(const bf16x8*)&rT[quad * 8];
        bf16x8 fb1c = *(const bf16x8*)&rT[32 + quad * 8];
        float tqc = nb[w * 256 + tt];
        float yvc = yb[w * 256 + tt];
        for (int st = 0; st < 16; ++st) {
            bf16x8 fb0n, fb1n;
            float tqn = 0.f, yvn = 0.f;
            if (st < 15) {
                int tnext = w * 256 + (st + 1) * 16 + tt;
                const unsigned short* rN = &Qb[(size_t)tnext * 512];
                fb0n = *(const bf16x8*)&rN[quad * 8];
                fb1n = *(const bf16x8*)&rN[32 + quad * 8];
                tqn = nb[tnext];
                yvn = yb[tnext];
            }
            #pragma unroll
            for (int tl = 0; tl < 4; ++tl) {
                f32x4 dot = {0.f, 0.f, 0.f, 0.f};
                dot = __builtin_amdgcn_mfma_f32_16x16x32_bf16(fa0[tl], fb0c, dot, 0, 0, 0);
                dot = __builtin_amdgcn_mfma_f32_16x16x32_bf16(fa1[tl], fb1c, dot, 0, 0, 0);
                #pragma unroll
                for (int g = 0; g < 4; ++g) {
                    float arg = fmaf(C025, dot[g], tqc);
                    float e = EXP2F(arg);
                    num[tl][g] = fmaf(e, yvc, num[tl][g]);
                    den[tl][g] += e;
                }
            }
            if (st < 15) { fb0c = fb0n; fb1c = fb1n; tqc = tqn; yvc = yvn; }
        }

        #pragma unroll
        for (int off = 1; off <= 8; off <<= 1)
            #pragma unroll
            for (int tl = 0; tl < 4; ++tl)
                #pragma unroll
                for (int g = 0; g < 4; ++g) {
                    num[tl][g] += __shfl_xor(num[tl][g], off);
                    den[tl][g] += __shfl_xor(den[tl][g], off);
                }
        if (tt == 0) {
            #pragma unroll
            for (int tl = 0; tl < 4; ++tl)
                #pragma unroll
                for (int g = 0; g < 4; ++g) {
                    redN[w][tl * 16 + quad * 4 + g] = num[tl][g];
                    redD[w][tl * 16 + quad * 4 + g] = den[tl][g];
                }
        }
        __syncthreads();
        if (tid < 64) {
            float xn = 0.f, xd = 0.f;
            #pragma unroll
            for (int ww = 0; ww < 8; ++ww) {
                xn += redN[ww][tid];
                xd += redD[ww][tid];
            }
            float x = xn / xd;
            out[bh * 2048 + s0 + tid] = 1.0f / (1.0f + EXP2F(-x * LOG2E));
        }
    }
}

extern "C" void kernel_launch(void* const* d_in, const int* in_sizes, int n_in,
                              void* d_out, int out_size, void* d_ws, size_t ws_size,
                              hipStream_t stream) {
    const float* X  = (const float*)d_in[0];
    const float* Wq = (const float*)d_in[1];
    const float* Wv = (const float*)d_in[2];
    float* outp = (float*)d_out;
    float* ws = (float*)d_ws;

    float* nl_ws = ws;                                        // 32768 floats
    float* y_ws  = ws + 32768;                                // 32768 floats
    unsigned int* cnt_ws = (unsigned int*)(ws + 65536);       // 16 x 128B counters
    unsigned short* Qh_ws = (unsigned short*)(ws + 66048);    // 2M bf16 (16B-aligned)

    hipMemsetAsync(cnt_ws, 0, 16 * CNT_STRIDE * 4, stream);   // zero barrier counters
    fused_k<<<512, 512, 0, stream>>>(X, Wq, Wv, Qh_ws, nl_ws, y_ws, cnt_ws, outp);
}

// Round 9
// 96.966 us; speedup vs baseline: 2.7013x; 1.0477x over previous
//
#include <hip/hip_runtime.h>

// Problem: B=2, S=2048, D=512, H=8, dh=64.
// R12: revert to the verified 2-kernel R5 structure (99.35us window; fused
// path after 5 fix rounds = 101.6us -> fusion's upside is ~0, abandoned).
// Ports the ONE fused-path win into it: XCD-aware block mapping (proved
// FETCH 51->10.5MB inside fused), plus R11's rotating-register prefetch.
//   qgemm_k (512x256): Q = X @ Wq via bf16 MFMA; fp32->bf16 in registers,
//     swizzled LDS staging, next-tile loads under MFMAs; t[h] = Wh^T Wv in
//     B staging. Mapping h=bid>>6, m0=(bid&63)*64 -> 8 blocks sharing an X
//     row-panel have equal bid%8 -> same XCD L2. Epilogue: Qh bf16,
//     nl = -0.125*log2e*||Q||, y = Q.t[h].
//   attn_k (512x512): out = sigmoid( softmax((2QQ^T - n_s - n_t)/8) @ y ).
//     -n_s cancels in softmax; exp2 args bounded -> fp32-safe. Mapping
//     bh=bid&15, tile=bid>>4 -> all 32 blocks of a bh on one XCD, Qh slice
//     (256KB) L2-resident. Waves own disjoint 256-row t-ranges; 1-deep
//     rotating prefetch; zero barriers in the main loop.

typedef __attribute__((ext_vector_type(8))) short bf16x8;
typedef __attribute__((ext_vector_type(4))) float f32x4;

#if __has_builtin(__builtin_amdgcn_exp2f)
#define EXP2F(x) __builtin_amdgcn_exp2f(x)
#else
#define EXP2F(x) exp2f(x)
#endif

#define LOG2E 1.44269504088896341f
#define C025  (0.25f * LOG2E)
#define C0125 (0.125f * LOG2E)

__device__ inline unsigned int f2b(float f) {  // fp32 -> bf16 bits, RNE
    unsigned int u = __float_as_uint(f);
    return (u + 0x7fffu + ((u >> 16) & 1u)) >> 16;
}

// swizzled LDS tile: row stride 64 bf16 (128B), 16B chunk c at (c ^ (row&7))
#define SWZ(row, c) ((row) * 64 + (((c) ^ ((row) & 7)) * 8))

// ---- Qh = bf16(X @ Wq), nl, y; t computed in-block ----
__global__ __launch_bounds__(256) void qgemm_k(const float* __restrict__ X,
                                               const float* __restrict__ Wq,
                                               const float* __restrict__ Wv,
                                               unsigned short* __restrict__ Qh,
                                               float* __restrict__ nl_out,
                                               float* __restrict__ y_out) {
    __shared__ __align__(16) unsigned short As[64 * 64];
    __shared__ __align__(16) unsigned short Bs[64 * 64];
    __shared__ float tsh[256];
    int tid = threadIdx.x;
    int bid = blockIdx.x;
    int h = bid >> 6;                   // XCD-local: same-m0 blocks share bid%8
    int m0 = (bid & 63) * 64;
    int n0 = h * 64;
    int w = tid >> 6, lane = tid & 63;
    int tt = lane & 15, quad = lane >> 4;

    // A staging: thread handles rows (tid>>3) and +32, 16B k-chunk (tid&7)
    int arow = tid >> 3, achk = tid & 7;
    // B staging: thread handles Wq column n0+(tid&63), k-chunks (tid>>6), +4
    int bc = tid & 63, bjg = tid >> 6;

    const float* Xa0 = &X[(m0 + arow) * 512 + achk * 8];
    const float* Xa1 = Xa0 + 32 * 512;
    const float* Wb  = &Wq[n0 + bc];

    float4 a00, a01, a10, a11;
    float bv[16], wv[16];
    float tp = 0.f;
    f32x4 acc[4] = {{0.f,0.f,0.f,0.f},{0.f,0.f,0.f,0.f},
                    {0.f,0.f,0.f,0.f},{0.f,0.f,0.f,0.f}};

#define K1_LOADS(K0)                                                     \
    do {                                                                 \
        a00 = *(const float4*)&Xa0[(K0)];                                \
        a01 = *(const float4*)&Xa0[(K0) + 4];                            \
        a10 = *(const float4*)&Xa1[(K0)];                                \
        a11 = *(const float4*)&Xa1[(K0) + 4];                            \
        _Pragma("unroll")                                                \
        for (int i = 0; i < 8; ++i) {                                    \
            bv[i]     = Wb[((K0) + bjg * 8 + i) * 512];                  \
            bv[8 + i] = Wb[((K0) + (bjg + 4) * 8 + i) * 512];            \
            wv[i]     = Wv[(K0) + bjg * 8 + i];                          \
            wv[8 + i] = Wv[(K0) + (bjg + 4) * 8 + i];                    \
        }                                                                \
    } while (0)

    K1_LOADS(0);
    for (int k0 = 0; k0 < 512; k0 += 64) {
        __syncthreads();                 // prev compute done reading LDS
        uint4 o;
        o.x = f2b(a00.x) | (f2b(a00.y) << 16);
        o.y = f2b(a00.z) | (f2b(a00.w) << 16);
        o.z = f2b(a01.x) | (f2b(a01.y) << 16);
        o.w = f2b(a01.z) | (f2b(a01.w) << 16);
        *(uint4*)&As[SWZ(arow, achk)] = o;
        o.x = f2b(a10.x) | (f2b(a10.y) << 16);
        o.y = f2b(a10.z) | (f2b(a10.w) << 16);
        o.z = f2b(a11.x) | (f2b(a11.y) << 16);
        o.w = f2b(a11.z) | (f2b(a11.w) << 16);
        *(uint4*)&As[SWZ(arow + 32, achk)] = o;
        o.x = f2b(bv[0]) | (f2b(bv[1]) << 16);
        o.y = f2b(bv[2]) | (f2b(bv[3]) << 16);
        o.z = f2b(bv[4]) | (f2b(bv[5]) << 16);
        o.w = f2b(bv[6]) | (f2b(bv[7]) << 16);
        *(uint4*)&Bs[SWZ(bc, bjg)] = o;
        o.x = f2b(bv[8])  | (f2b(bv[9])  << 16);
        o.y = f2b(bv[10]) | (f2b(bv[11]) << 16);
        o.z = f2b(bv[12]) | (f2b(bv[13]) << 16);
        o.w = f2b(bv[14]) | (f2b(bv[15]) << 16);
        *(uint4*)&Bs[SWZ(bc, bjg + 4)] = o;
        #pragma unroll
        for (int i = 0; i < 16; ++i) tp = fmaf(bv[i], wv[i], tp);  // t[h] partial
        __syncthreads();
        if (k0 < 448) K1_LOADS(k0 + 64);  // next-tile loads overlap MFMAs below
        int ar = w * 16 + tt;
        bf16x8 fa0 = *(const bf16x8*)&As[SWZ(ar, quad)];
        bf16x8 fa1 = *(const bf16x8*)&As[SWZ(ar, quad + 4)];
        #pragma unroll
        for (int ct = 0; ct < 4; ++ct) {
            int br = ct * 16 + tt;
            bf16x8 fb0 = *(const bf16x8*)&Bs[SWZ(br, quad)];
            bf16x8 fb1 = *(const bf16x8*)&Bs[SWZ(br, quad + 4)];
            acc[ct] = __builtin_amdgcn_mfma_f32_16x16x32_bf16(fa0, fb0, acc[ct], 0, 0, 0);
            acc[ct] = __builtin_amdgcn_mfma_f32_16x16x32_bf16(fa1, fb1, acc[ct], 0, 0, 0);
        }
    }

    // reduce t partials: 4 k-groups per column
    tsh[bjg * 64 + bc] = tp;
    __syncthreads();
    float tv[4];
    #pragma unroll
    for (int ct = 0; ct < 4; ++ct) {
        int c = ct * 16 + tt;
        tv[ct] = tsh[c] + tsh[64 + c] + tsh[128 + c] + tsh[192 + c];
    }

    float s2[4] = {0.f,0.f,0.f,0.f}, yp[4] = {0.f,0.f,0.f,0.f};
    #pragma unroll
    for (int ct = 0; ct < 4; ++ct)
        #pragma unroll
        for (int g = 0; g < 4; ++g) {
            float v = acc[ct][g];
            s2[g] = fmaf(v, v, s2[g]);
            yp[g] = fmaf(v, tv[ct], yp[g]);
            Qh[(m0 + w * 16 + quad * 4 + g) * 512 + n0 + ct * 16 + tt] =
                (unsigned short)f2b(v);
        }
    #pragma unroll
    for (int off = 1; off <= 8; off <<= 1)
        #pragma unroll
        for (int g = 0; g < 4; ++g) {
            s2[g] += __shfl_xor(s2[g], off);
            yp[g] += __shfl_xor(yp[g], off);
        }
    if (tt == 0) {
        int bb = m0 >> 11;
        #pragma unroll
        for (int g = 0; g < 4; ++g) {
            int row = m0 + w * 16 + quad * 4 + g;
            int idx = ((bb * 8 + h) << 11) + (row & 2047);
            nl_out[idx] = -C0125 * sqrtf(s2[g]);   // pre-scaled
            y_out[idx]  = yp[g];
        }
    }
}

// ---- attention: 64 q-rows/block; 8 waves own disjoint 256-row t-ranges ----
__global__ __launch_bounds__(512, 4) void attn_k(const unsigned short* __restrict__ Qh,
                                                 const float* __restrict__ nl_in,
                                                 const float* __restrict__ y_in,
                                                 float* __restrict__ out) {
    __shared__ float redN[8][64];
    __shared__ float redD[8][64];
    int tid = threadIdx.x;
    int bid = blockIdx.x;
    int bh = bid & 15;                  // all 32 blocks of bh share bid%8 -> XCD
    int tile = bid >> 4;
    int s0 = tile * 64;
    int b = bh >> 3, h = bh & 7;
    const unsigned short* __restrict__ Qb = Qh + (size_t)(b * 2048) * 512 + h * 64;
    const float* __restrict__ nb = nl_in + bh * 2048;
    const float* __restrict__ yb = y_in + bh * 2048;
    int w = tid >> 6, lane = tid & 63;
    int tt = lane & 15, quad = lane >> 4;

    // A fragments for 4 s-tiles (held in registers for the whole kernel)
    bf16x8 fa0[4], fa1[4];
    #pragma unroll
    for (int tl = 0; tl < 4; ++tl) {
        const unsigned short* r = &Qb[(size_t)(s0 + tl * 16 + tt) * 512];
        fa0[tl] = *(const bf16x8*)&r[quad * 8];
        fa1[tl] = *(const bf16x8*)&r[32 + quad * 8];
    }
    f32x4 num[4] = {{0.f,0.f,0.f,0.f},{0.f,0.f,0.f,0.f},
                    {0.f,0.f,0.f,0.f},{0.f,0.f,0.f,0.f}};
    f32x4 den[4] = {{0.f,0.f,0.f,0.f},{0.f,0.f,0.f,0.f},
                    {0.f,0.f,0.f,0.f},{0.f,0.f,0.f,0.f}};

    // wave's t-range [w*256, w*256+256), rotating-register 1-deep prefetch
    const unsigned short* rT = &Qb[(size_t)(w * 256 + tt) * 512];
    bf16x8 fb0c = *(const bf16x8*)&rT[quad * 8];
    bf16x8 fb1c = *(const bf16x8*)&rT[32 + quad * 8];
    float tqc = nb[w * 256 + tt];
    float yvc = yb[w * 256 + tt];
    for (int st = 0; st < 16; ++st) {
        bf16x8 fb0n, fb1n;
        float tqn = 0.f, yvn = 0.f;
        if (st < 15) {
            int tnext = w * 256 + (st + 1) * 16 + tt;
            const unsigned short* rN = &Qb[(size_t)tnext * 512];
            fb0n = *(const bf16x8*)&rN[quad * 8];
            fb1n = *(const bf16x8*)&rN[32 + quad * 8];
            tqn = nb[tnext];
            yvn = yb[tnext];
        }
        #pragma unroll
        for (int tl = 0; tl < 4; ++tl) {
            f32x4 dot = {0.f, 0.f, 0.f, 0.f};
            dot = __builtin_amdgcn_mfma_f32_16x16x32_bf16(fa0[tl], fb0c, dot, 0, 0, 0);
            dot = __builtin_amdgcn_mfma_f32_16x16x32_bf16(fa1[tl], fb1c, dot, 0, 0, 0);
            #pragma unroll
            for (int g = 0; g < 4; ++g) {
                float arg = fmaf(C025, dot[g], tqc);
                float e = EXP2F(arg);
                num[tl][g] = fmaf(e, yvc, num[tl][g]);
                den[tl][g] += e;
            }
        }
        if (st < 15) { fb0c = fb0n; fb1c = fb1n; tqc = tqn; yvc = yvn; }
    }

    // reduce over 16 t-lanes, then across the 8 waves via LDS
    #pragma unroll
    for (int off = 1; off <= 8; off <<= 1)
        #pragma unroll
        for (int tl = 0; tl < 4; ++tl)
            #pragma unroll
            for (int g = 0; g < 4; ++g) {
                num[tl][g] += __shfl_xor(num[tl][g], off);
                den[tl][g] += __shfl_xor(den[tl][g], off);
            }
    if (tt == 0) {
        #pragma unroll
        for (int tl = 0; tl < 4; ++tl)
            #pragma unroll
            for (int g = 0; g < 4; ++g) {
                redN[w][tl * 16 + quad * 4 + g] = num[tl][g];
                redD[w][tl * 16 + quad * 4 + g] = den[tl][g];
            }
    }
    __syncthreads();
    if (tid < 64) {
        float xn = 0.f, xd = 0.f;
        #pragma unroll
        for (int ww = 0; ww < 8; ++ww) {
            xn += redN[ww][tid];
            xd += redD[ww][tid];
        }
        float x = xn / xd;
        out[bh * 2048 + s0 + tid] = 1.0f / (1.0f + EXP2F(-x * LOG2E));
    }
}

extern "C" void kernel_launch(void* const* d_in, const int* in_sizes, int n_in,
                              void* d_out, int out_size, void* d_ws, size_t ws_size,
                              hipStream_t stream) {
    const float* X  = (const float*)d_in[0];
    const float* Wq = (const float*)d_in[1];
    const float* Wv = (const float*)d_in[2];
    float* ws = (float*)d_ws;

    float* nl_ws = ws;                                      // 32768 floats
    float* y_ws  = ws + 32768;                              // 32768 floats
    unsigned short* Qh_ws = (unsigned short*)(ws + 65536);  // 2M bf16

    qgemm_k<<<512, 256, 0, stream>>>(X, Wq, Wv, Qh_ws, nl_ws, y_ws);
    attn_k<<<512, 512, 0, stream>>>(Qh_ws, nl_ws, y_ws, (float*)d_out);
}